// Round 11
// baseline (243.667 us; speedup 1.0000x reference)
//
#include <hip/hip_runtime.h>

#define BB   1024
#define TT   512
#define NIN  28
#define NOUT 28
#define NS   4
#define MM   7
#define WW   457          // TT - NIN - NOUT + 1
#define SLEN 519          // MM + 1 + TT - 1
#define EMB  9            // 1 + 1 + MM

#define OUT1_SZ (WW * BB * 144)
#define OUT2_SZ (WW * BB * 28)
#define OUT3_SZ (BB * TT)
#define OUT4_SZ (BB * SLEN)

#define CH   32
#define NCH  (TT / CH)    // 16

typedef float f4 __attribute__((ext_vector_type(4)));

__device__ __forceinline__ f4 ld4u(const float* p) {   // 4B-aligned 16B load
    f4 v;
    __builtin_memcpy(&v, p, sizeof(f4));
    return v;
}

// ---------------------------------------------------------------------------
// Kernel 1: ES scan (unchanged, ~10 us).
// ---------------------------------------------------------------------------
__global__ __launch_bounds__(64) void es_scan(const float* __restrict__ Y,
        const int* __restrict__ idxs, const float* __restrict__ EW,
        float* __restrict__ levels, float* __restrict__ seas) {
    __shared__ float yl[64][CH + 1];
    __shared__ float se[64][CH + 1];
    const int tid = threadIdx.x;
    const int b0  = blockIdx.x << 6;
    const int b   = b0 + tid;

    const float* e = EW + idxs[b] * EMB;
    const float lev_sms  = 1.0f / (1.0f + __expf(-e[0]));
    const float seas_sms = 1.0f / (1.0f + __expf(-e[1]));
    const float a_l = 1.0f - lev_sms;
    const float a_s = 1.0f - seas_sms;

    float buf[MM];
    const float is0 = __expf(e[2]);
    {
        float* srow = seas + b * SLEN;
        srow[0] = is0;
#pragma unroll
        for (int k = 1; k < MM; ++k) {
            float v = __expf(e[2 + k]);
            srow[k] = v;
            buf[k - 1] = v;
        }
        buf[MM - 1] = is0;
    }

    f4 pf[8];
#pragma unroll
    for (int k = 0; k < 8; ++k) {
        int flat = (k << 6) + tid;
        int r = flat >> 3, q = flat & 7;
        pf[k] = *reinterpret_cast<const f4*>(Y + (b0 + r) * TT + (q << 2));
    }

    float lev = 0.0f;

#define ES_STEP(TTI)                                                        \
    {                                                                       \
        float y  = yreg[TTI];                                               \
        float st = buf[0];                                                  \
        lev = lev_sms * __fdividef(y, st) + a_l * lev;                      \
        float ns = seas_sms * __fdividef(y, lev) + a_s * st;                \
        buf[0] = buf[1]; buf[1] = buf[2]; buf[2] = buf[3];                  \
        buf[3] = buf[4]; buf[4] = buf[5]; buf[5] = buf[6];                  \
        buf[6] = ns;                                                        \
        yl[tid][TTI] = lev;                                                 \
        se[tid][TTI] = ns;                                                  \
    }

    for (int c = 0; c < NCH; ++c) {
        __syncthreads();
#pragma unroll
        for (int k = 0; k < 8; ++k) {
            int flat = (k << 6) + tid;
            int r = flat >> 3, q = flat & 7;
            float* dst = &yl[r][q << 2];
            dst[0] = pf[k].x; dst[1] = pf[k].y; dst[2] = pf[k].z; dst[3] = pf[k].w;
        }
        __syncthreads();
        if (c < NCH - 1) {
#pragma unroll
            for (int k = 0; k < 8; ++k) {
                int flat = (k << 6) + tid;
                int r = flat >> 3, q = flat & 7;
                pf[k] = *reinterpret_cast<const f4*>(
                    Y + (b0 + r) * TT + (c + 1) * CH + (q << 2));
            }
        }

        float yreg[CH];
#pragma unroll
        for (int tt = 0; tt < CH; ++tt) yreg[tt] = yl[tid][tt];

        if (c == 0) {
            lev = __fdividef(yreg[0], is0);
            yl[tid][0] = lev;
            se[tid][0] = is0;
#pragma unroll
            for (int tt = 1; tt < CH; ++tt) ES_STEP(tt)
        } else {
#pragma unroll
            for (int tt = 0; tt < CH; ++tt) ES_STEP(tt)
        }
        __syncthreads();

#pragma unroll
        for (int k = 0; k < CH; ++k) {
            int flat = (k << 6) + tid;
            int r    = flat >> 5;
            int col  = flat & 31;
            levels[(b0 + r) * TT   + c * CH + col]      = yl[r][col];
            seas  [(b0 + r) * SLEN + MM + c * CH + col] = se[r][col];
        }
    }
#undef ES_STEP
}

// ---------------------------------------------------------------------------
// Kernel 2 (fused): out1 + out2/out5.
// blockIdx%3: {0,1} -> out1 half-tile (2 rows x half-w, 30.5KB LDS),
//             {2}   -> out25 (2 rows x all w, Y/M shift replicas).
// Fixed role per thread (class branch hoisted out of g-loop); strength-
// reduced store offsets; 512 thr x 4 blocks/CU = 100% occupancy.
// ---------------------------------------------------------------------------
__global__ __launch_bounds__(512) void fused_stream(const float* __restrict__ S,
        const float* __restrict__ Y, const float* __restrict__ X,
        const float* __restrict__ mask, const float* __restrict__ levels,
        const float* __restrict__ seas, f4* __restrict__ out1,
        f4* __restrict__ out2, f4* __restrict__ out5) {
    __shared__ __align__(16) f4 U[1952];      // 31,232 B (union)

    const int tid = threadIdx.x;
    const int q3  = blockIdx.x / 3;
    const int r3  = blockIdx.x - q3 * 3;

    if (r3 < 2) {
        // ================= out1 =================
        const int id     = 2 * q3 + r3;       // 0..1023
        const int b0     = id & ~1;           // 2-row pair
        const int h      = id & 1;            // w-half
        const int gstart = h ? 229 : 0;
        const int gend   = h ? 457 : 229;
        const int whbase = h ? 57 : 0;

        float* LB  = (float*)(U + 1152);      // LYS: [bl*520 + t], 1040 f
        float* LLB = LB + 1040;               // LL:  [bl*512 + t], 1024 f

        // stage per-element logs (coalesced, L2-hot)
        for (int u = tid; u < 1024; u += 512) {
            int bl = u >> 9, t = u & 511;
            int b  = b0 + bl;
            LLB[bl * 512 + t] = __logf(levels[b * TT + t]);
            LB[bl * 520 + t]  = __logf(Y[b * TT + t]) - __logf(seas[b * SLEN + t]);
        }
        // stage X shift-replicas: U[(s*4 + bl*2 + ch)*72 + k]
        for (int u = tid; u < 1152; u += 512) {
            int k  = u % 72;
            int c3 = u / 72;                  // s*4 + bl*2 + ch
            int ch = c3 & 1, bl = (c3 >> 1) & 1, s = c3 >> 2;
            int base = 4 * (k + whbase) + s;
            if (base > 508) base = 508;
            U[u] = ld4u(X + (size_t)((b0 + bl) * 2 + ch) * TT + base);
        }
        f4 Sv0 = *reinterpret_cast<const f4*>(S + b0 * NS);
        f4 Sv1 = *reinterpret_cast<const f4*>(S + (b0 + 1) * NS);
        __syncthreads();

        if (tid < 504) {
            const int go  = tid / 72;         // 0..6
            const int rr  = tid % 72;
            const int bl  = rr >= 36 ? 1 : 0;
            const int col = rr - 36 * bl;
            const int g0  = gstart + go;
            int off = (((g0) << 10) + b0 + bl) * 36 + col;
            const int OST = 7 * 1024 * 36;    // g += 7 step

            if (col < 7) {
                const float* p  = LB  + bl * 520 + g0 + 4 * col;
                const float* lp = LLB + bl * 512 + g0 + 27;
                for (int g = g0; g < gend; g += 7, p += 7, lp += 7, off += OST) {
                    float ll = *lp;
                    f4 v;
                    v.x = p[0] - ll; v.y = p[1] - ll;
                    v.z = p[2] - ll; v.w = p[3] - ll;
                    __builtin_nontemporal_store(v, &out1[off]);
                }
            } else if (col < 35) {
                const int ch = col >= 21 ? 1 : 0;
                const int jj = col - 7 - 14 * ch;
                const int cb = (bl * 2 + ch) * 72 + jj - whbase;
                for (int g = g0; g < gend; g += 7, off += OST) {
                    f4 v = U[(g & 3) * 288 + cb + (g >> 2)];
                    __builtin_nontemporal_store(v, &out1[off]);
                }
            } else {
                const f4 v = bl ? Sv1 : Sv0;
                for (int g = g0; g < gend; g += 7, off += OST) {
                    __builtin_nontemporal_store(v, &out1[off]);
                }
            }
        }
    } else {
        // ================= out2 + out5 =================
        const int b0 = q3 * 2;
        // U[(s*2+bl)*122 + k] = Y[bl][28+4k+s ..]; U[976 + ...] = mask
        for (int u = tid; u < 1952; u += 512) {
            int k    = u % 122;
            int c2   = u / 122;               // 0..15
            int half = c2 >> 3;
            int cc   = c2 & 7;                // s*2 + bl
            int bl   = cc & 1, s = cc >> 1;
            int base = 28 + 4 * k + s;
            if (base > 508) base = 508;
            const float* src = half ? (mask + (size_t)(b0 + bl) * TT)
                                    : (Y    + (size_t)(b0 + bl) * TT);
            U[u] = ld4u(src + base);
        }
        __syncthreads();

        if (tid < 504) {
            const int go  = tid / 28;         // 0..17
            const int rr  = tid % 28;
            const int arr = rr >= 14 ? 1 : 0;
            const int rem = rr - 14 * arr;
            const int bl  = rem >= 7 ? 1 : 0;
            const int jj  = rem - 7 * bl;
            const int sb  = arr * 976 + bl * 122 + jj;
            f4* dst = arr ? out5 : out2;
            int off = ((go << 10) + b0 + bl) * 7 + jj;
            const int OST = 18 * 1024 * 7;    // g += 18 step
            for (int g = go; g < WW; g += 18, off += OST) {
                f4 v = U[sb + (g & 3) * 244 + (g >> 2)];
                __builtin_nontemporal_store(v, &dst[off]);
            }
        }
    }
}

extern "C" void kernel_launch(void* const* d_in, const int* in_sizes, int n_in,
                              void* d_out, int out_size, void* d_ws, size_t ws_size,
                              hipStream_t stream) {
    const float* S    = (const float*)d_in[0];
    const float* Y    = (const float*)d_in[1];
    const float* X    = (const float*)d_in[2];
    const int*   idxs = (const int*)d_in[3];
    const float* mask = (const float*)d_in[4];
    const float* EW   = (const float*)d_in[5];

    float* out  = (float*)d_out;
    float* out1 = out;
    float* out2 = out1 + OUT1_SZ;
    float* out3 = out2 + OUT2_SZ;        // levels
    float* out4 = out3 + OUT3_SZ;        // seasonalities
    float* out5 = out4 + OUT4_SZ;        // mask_w

    es_scan<<<16, 64, 0, stream>>>(Y, idxs, EW, out3, out4);
    fused_stream<<<1536, 512, 0, stream>>>(S, Y, X, mask, out3, out4,
                                           (f4*)out1, (f4*)out2, (f4*)out5);
}

// Round 12
// 158.964 us; speedup vs baseline: 1.5328x; 1.5328x over previous
//
#include <hip/hip_runtime.h>

#define BB   1024
#define TT   512
#define NIN  28
#define NOUT 28
#define NS   4
#define MM   7
#define WW   457          // TT - NIN - NOUT + 1
#define SLEN 519          // MM + 1 + TT - 1
#define EMB  9            // 1 + 1 + MM

#define OUT1_SZ (WW * BB * 144)
#define OUT2_SZ (WW * BB * 28)
#define OUT3_SZ (BB * TT)
#define OUT4_SZ (BB * SLEN)

#define CH   32
#define NCH  (TT / CH)    // 16
#define NF2  (WW * BB * 7)

typedef float f4 __attribute__((ext_vector_type(4)));

__device__ __forceinline__ f4 ld4u(const float* p) {   // 4B-aligned 16B load
    f4 v;
    __builtin_memcpy(&v, p, sizeof(f4));
    return v;
}

// ---------------------------------------------------------------------------
// Kernel 1 (fused): blocks 0..15 = ES scan (256 threads: coop I/O by all,
// recurrence by tid<64; barriers uniform). blocks 16..2063 = out2/out5
// streaming (no LDS use, grid-stride, full-wave dense nt stores).
// ---------------------------------------------------------------------------
__global__ __launch_bounds__(256, 8) void k_scan_out25(
        const float* __restrict__ Y, const int* __restrict__ idxs,
        const float* __restrict__ EW, const float* __restrict__ mask,
        float* __restrict__ levels, float* __restrict__ seas,
        f4* __restrict__ out2, f4* __restrict__ out5) {
    __shared__ float yl[64][CH + 1];
    __shared__ float se[64][CH + 1];

    const int tid = threadIdx.x;

    if (blockIdx.x < 16) {
        // ======================= ES scan =======================
        const int b0 = blockIdx.x << 6;
        const int bs = b0 + (tid & 63);           // in-bounds for all tid

        const float* e = EW + idxs[bs] * EMB;
        const float lev_sms  = 1.0f / (1.0f + __expf(-e[0]));
        const float seas_sms = 1.0f / (1.0f + __expf(-e[1]));
        const float a_l = 1.0f - lev_sms;
        const float a_s = 1.0f - seas_sms;

        float buf[MM];
        const float is0 = __expf(e[2]);
        {
            float* srow = seas + bs * SLEN;
            if (tid < 64) srow[0] = is0;
#pragma unroll
            for (int k = 1; k < MM; ++k) {
                float v = __expf(e[2 + k]);
                if (tid < 64) srow[k] = v;
                buf[k - 1] = v;
            }
            buf[MM - 1] = is0;
        }

        // prefetch chunk 0: 512 f4 / 256 thr = 2 each
        f4 pf[2];
#pragma unroll
        for (int k = 0; k < 2; ++k) {
            int flat = (k << 8) + tid;            // 0..511
            int r = flat >> 3, q = flat & 7;
            pf[k] = *reinterpret_cast<const f4*>(Y + (b0 + r) * TT + (q << 2));
        }

        float lev = 0.0f;

#define ES_STEP(TTI)                                                        \
    {                                                                       \
        float y  = yreg[TTI];                                               \
        float st = buf[0];                                                  \
        lev = lev_sms * __fdividef(y, st) + a_l * lev;                      \
        float ns = seas_sms * __fdividef(y, lev) + a_s * st;                \
        buf[0] = buf[1]; buf[1] = buf[2]; buf[2] = buf[3];                  \
        buf[3] = buf[4]; buf[4] = buf[5]; buf[5] = buf[6];                  \
        buf[6] = ns;                                                        \
        yl[tid][TTI] = lev;                                                 \
        se[tid][TTI] = ns;                                                  \
    }

        for (int c = 0; c < NCH; ++c) {
            __syncthreads();                      // prev coop-store reads done
#pragma unroll
            for (int k = 0; k < 2; ++k) {
                int flat = (k << 8) + tid;
                int r = flat >> 3, q = flat & 7;
                float* dst = &yl[r][q << 2];
                dst[0] = pf[k].x; dst[1] = pf[k].y;
                dst[2] = pf[k].z; dst[3] = pf[k].w;
            }
            __syncthreads();
            if (c < NCH - 1) {
#pragma unroll
                for (int k = 0; k < 2; ++k) {
                    int flat = (k << 8) + tid;
                    int r = flat >> 3, q = flat & 7;
                    pf[k] = *reinterpret_cast<const f4*>(
                        Y + (b0 + r) * TT + (c + 1) * CH + (q << 2));
                }
            }

            if (tid < 64) {
                float yreg[CH];
#pragma unroll
                for (int tt = 0; tt < CH; ++tt) yreg[tt] = yl[tid][tt];

                if (c == 0) {
                    lev = __fdividef(yreg[0], is0);
                    yl[tid][0] = lev;
                    se[tid][0] = is0;             // s0 at seas index MM
#pragma unroll
                    for (int tt = 1; tt < CH; ++tt) ES_STEP(tt)
                } else {
#pragma unroll
                    for (int tt = 0; tt < CH; ++tt) ES_STEP(tt)
                }
            }
            __syncthreads();

            // coop store: 4096 floats / 256 thr
#pragma unroll
            for (int k = 0; k < 8; ++k) {
                int flat = (k << 8) + tid;        // 0..2047
                int r    = flat >> 5;
                int col  = flat & 31;
                levels[(b0 + r) * TT   + c * CH + col]      = yl[r][col];
                seas  [(b0 + r) * SLEN + MM + c * CH + col] = se[r][col];
            }
        }
#undef ES_STEP
    } else {
        // ======================= out2 + out5 =======================
        const int id = blockIdx.x - 16;           // 0..2047
        for (int i = (id << 8) + tid; i < NF2; i += 2048 * 256) {
            int wb = i / 7;
            int j  = i - wb * 7;
            int b  = wb & (BB - 1);
            int w  = wb >> 10;
            int base = w + NIN + (j << 2);
            f4 vy = ld4u(Y    + b * TT + base);
            f4 vm = ld4u(mask + b * TT + base);
            __builtin_nontemporal_store(vy, &out2[i]);
            __builtin_nontemporal_store(vm, &out5[i]);
        }
    }
}

// ---------------------------------------------------------------------------
// Kernel 2: out1. 2048 blocks = (b-pair) x (w-quarter); 16.4KB LDS scalar
// staging -> 8 blocks/CU co-resident (100% occupancy target).
// Value branch inside the loop; store OUTSIDE branches = full-wave dense.
// ---------------------------------------------------------------------------
#define QW 115

__global__ __launch_bounds__(256, 8) void k_out1(const float* __restrict__ S,
        const float* __restrict__ Y, const float* __restrict__ X,
        const float* __restrict__ levels, const float* __restrict__ seas,
        f4* __restrict__ out1) {
    __shared__ float Xs[2][2][TT];    // [bl][ch][t]
    __shared__ float LYSp[2][TT];     // log Y - log seas
    __shared__ float LLs[2][TT];      // log levels

    const int tid = threadIdx.x;
    const int p   = blockIdx.x >> 2;          // b-pair 0..511
    const int qt  = blockIdx.x & 3;           // w-quarter
    const int b0  = p << 1;
    const int g0  = qt * QW;
    const int NW  = (qt == 3) ? (WW - 3 * QW) : QW;   // 115,115,115,112

    // stage X (scalar, coalesced)
    for (int u = tid; u < 2048; u += 256) {
        int bl = u >> 10, ch = (u >> 9) & 1, t = u & 511;
        Xs[bl][ch][t] = X[(size_t)((b0 + bl) * 2 + ch) * TT + t];
    }
    // stage logs
    for (int u = tid; u < 1024; u += 256) {
        int bl = u >> 9, t = u & 511;
        int b  = b0 + bl;
        LLs[bl][t]  = __logf(levels[b * TT + t]);
        LYSp[bl][t] = __logf(Y[b * TT + t]) - __logf(seas[b * SLEN + t]);
    }
    f4 Sv0 = *reinterpret_cast<const f4*>(S + b0 * NS);
    f4 Sv1 = *reinterpret_cast<const f4*>(S + (b0 + 1) * NS);
    __syncthreads();

    const int NJ = NW * 72;
    for (int jj = tid; jj < NJ; jj += 256) {
        int grel = jj / 72;
        int r    = jj - grel * 72;
        int g    = g0 + grel;
        int bl   = (r >= 36) ? 1 : 0;
        int col  = r - 36 * bl;
        f4 v;
        if (col < 7) {                          // log insample
            int t    = g + (col << 2);
            float ll = LLs[bl][g + 27];
            v.x = LYSp[bl][t]     - ll; v.y = LYSp[bl][t + 1] - ll;
            v.z = LYSp[bl][t + 2] - ll; v.w = LYSp[bl][t + 3] - ll;
        } else if (col < 35) {                  // X windows
            int ch = (col >= 21) ? 1 : 0;
            int t  = g + ((col - 7 - 14 * ch) << 2);
            v.x = Xs[bl][ch][t];     v.y = Xs[bl][ch][t + 1];
            v.z = Xs[bl][ch][t + 2]; v.w = Xs[bl][ch][t + 3];
        } else {                                // statics
            v = bl ? Sv1 : Sv0;
        }
        __builtin_nontemporal_store(v, &out1[((g << 10) + b0 + bl) * 36 + col]);
    }
}

extern "C" void kernel_launch(void* const* d_in, const int* in_sizes, int n_in,
                              void* d_out, int out_size, void* d_ws, size_t ws_size,
                              hipStream_t stream) {
    const float* S    = (const float*)d_in[0];
    const float* Y    = (const float*)d_in[1];
    const float* X    = (const float*)d_in[2];
    const int*   idxs = (const int*)d_in[3];
    const float* mask = (const float*)d_in[4];
    const float* EW   = (const float*)d_in[5];

    float* out  = (float*)d_out;
    float* out1 = out;
    float* out2 = out1 + OUT1_SZ;
    float* out3 = out2 + OUT2_SZ;        // levels
    float* out4 = out3 + OUT3_SZ;        // seasonalities
    float* out5 = out4 + OUT4_SZ;        // mask_w

    k_scan_out25<<<2064, 256, 0, stream>>>(Y, idxs, EW, mask, out3, out4,
                                           (f4*)out2, (f4*)out5);
    k_out1<<<2048, 256, 0, stream>>>(S, Y, X, out3, out4, (f4*)out1);
}

// Round 13
// 149.443 us; speedup vs baseline: 1.6305x; 1.0637x over previous
//
#include <hip/hip_runtime.h>

#define BB   1024
#define TT   512
#define NIN  28
#define NOUT 28
#define NS   4
#define MM   7
#define WW   457          // TT - NIN - NOUT + 1
#define SLEN 519          // MM + 1 + TT - 1
#define EMB  9            // 1 + 1 + MM

#define OUT1_SZ (WW * BB * 144)
#define OUT2_SZ (WW * BB * 28)
#define OUT3_SZ (BB * TT)
#define OUT4_SZ (BB * SLEN)

#define CH   32
#define NCH  (TT / CH)    // 16

typedef float f4 __attribute__((ext_vector_type(4)));

__device__ __forceinline__ f4 ld4u(const float* p) {   // 4B-aligned 16B load
    f4 v;
    __builtin_memcpy(&v, p, sizeof(f4));
    return v;
}

// bijective XCD-chunked w map for 457 blocks (q=57, r=1; m204 formula)
__device__ __forceinline__ int wmap(int orig) {
    int xcd = orig & 7, idx = orig >> 3;
    return (xcd == 0) ? idx : 58 + (xcd - 1) * 57 + idx;
}

// ---------------------------------------------------------------------------
// Kernel 1: ES scan (R4 version, proven ~10 us).
// ---------------------------------------------------------------------------
__global__ __launch_bounds__(64) void es_scan(const float* __restrict__ Y,
        const int* __restrict__ idxs, const float* __restrict__ EW,
        float* __restrict__ levels, float* __restrict__ seas) {
    __shared__ float yl[64][CH + 1];
    __shared__ float se[64][CH + 1];
    const int tid = threadIdx.x;
    const int b0  = blockIdx.x << 6;
    const int b   = b0 + tid;

    const float* e = EW + idxs[b] * EMB;
    const float lev_sms  = 1.0f / (1.0f + __expf(-e[0]));
    const float seas_sms = 1.0f / (1.0f + __expf(-e[1]));
    const float a_l = 1.0f - lev_sms;
    const float a_s = 1.0f - seas_sms;

    float buf[MM];
    const float is0 = __expf(e[2]);
    {
        float* srow = seas + b * SLEN;
        srow[0] = is0;
#pragma unroll
        for (int k = 1; k < MM; ++k) {
            float v = __expf(e[2 + k]);
            srow[k] = v;
            buf[k - 1] = v;
        }
        buf[MM - 1] = is0;
    }

    f4 pf[8];
#pragma unroll
    for (int k = 0; k < 8; ++k) {
        int flat = (k << 6) + tid;
        int r = flat >> 3, q = flat & 7;
        pf[k] = *reinterpret_cast<const f4*>(Y + (b0 + r) * TT + (q << 2));
    }

    float lev = 0.0f;

#define ES_STEP(TTI)                                                        \
    {                                                                       \
        float y  = yreg[TTI];                                               \
        float st = buf[0];                                                  \
        lev = lev_sms * __fdividef(y, st) + a_l * lev;                      \
        float ns = seas_sms * __fdividef(y, lev) + a_s * st;                \
        buf[0] = buf[1]; buf[1] = buf[2]; buf[2] = buf[3];                  \
        buf[3] = buf[4]; buf[4] = buf[5]; buf[5] = buf[6];                  \
        buf[6] = ns;                                                        \
        yl[tid][TTI] = lev;                                                 \
        se[tid][TTI] = ns;                                                  \
    }

    for (int c = 0; c < NCH; ++c) {
        __syncthreads();
#pragma unroll
        for (int k = 0; k < 8; ++k) {
            int flat = (k << 6) + tid;
            int r = flat >> 3, q = flat & 7;
            float* dst = &yl[r][q << 2];
            dst[0] = pf[k].x; dst[1] = pf[k].y; dst[2] = pf[k].z; dst[3] = pf[k].w;
        }
        __syncthreads();
        if (c < NCH - 1) {
#pragma unroll
            for (int k = 0; k < 8; ++k) {
                int flat = (k << 6) + tid;
                int r = flat >> 3, q = flat & 7;
                pf[k] = *reinterpret_cast<const f4*>(
                    Y + (b0 + r) * TT + (c + 1) * CH + (q << 2));
            }
        }

        float yreg[CH];
#pragma unroll
        for (int tt = 0; tt < CH; ++tt) yreg[tt] = yl[tid][tt];

        if (c == 0) {
            lev = __fdividef(yreg[0], is0);
            yl[tid][0] = lev;
            se[tid][0] = is0;
#pragma unroll
            for (int tt = 1; tt < CH; ++tt) ES_STEP(tt)
        } else {
#pragma unroll
            for (int tt = 0; tt < CH; ++tt) ES_STEP(tt)
        }
        __syncthreads();

#pragma unroll
        for (int k = 0; k < CH; ++k) {
            int flat = (k << 6) + tid;
            int r    = flat >> 5;
            int col  = flat & 31;
            levels[(b0 + r) * TT   + c * CH + col]      = yl[r][col];
            seas  [(b0 + r) * SLEN + MM + c * CH + col] = se[r][col];
        }
    }
#undef ES_STEP
}

// ---------------------------------------------------------------------------
// Kernel 2: precompute LL[b][t] = log(levels), LYS[b][t] = log(Y) - log(seas)
// into d_ws (4 MB). 512 blocks x 256 thr, one f4 per thread. ~3 us.
// ---------------------------------------------------------------------------
__global__ __launch_bounds__(256) void k_pre(const float* __restrict__ levels,
        const float* __restrict__ seas, const float* __restrict__ Y,
        float* __restrict__ LL, float* __restrict__ LYS) {
    int u  = blockIdx.x * 256 + threadIdx.x;    // f4 index < 131072
    int b  = u >> 7;
    int t4 = (u & 127) << 2;
    f4 lv = *reinterpret_cast<const f4*>(levels + b * TT + t4);
    f4 yv = *reinterpret_cast<const f4*>(Y      + b * TT + t4);
    f4 sv = ld4u(seas + b * SLEN + t4);
    f4 a, c;
    a.x = __logf(lv.x); a.y = __logf(lv.y); a.z = __logf(lv.z); a.w = __logf(lv.w);
    c.x = __logf(yv.x) - __logf(sv.x);
    c.y = __logf(yv.y) - __logf(sv.y);
    c.z = __logf(yv.z) - __logf(sv.z);
    c.w = __logf(yv.w) - __logf(sv.w);
    *reinterpret_cast<f4*>(LL  + b * TT + t4) = a;
    *reinterpret_cast<f4*>(LYS + b * TT + t4) = c;
}

// ---------------------------------------------------------------------------
// Kernel 3: out1, w-major. Block owns out1[w] = 576KB CONTIGUOUS; store
// offset == loop index (one sequential stream per block, 457 streams).
// Reads straight from global (L2-hot; XCD-chunked w map for locality).
// PRE=1: logs from d_ws; PRE=0 fallback computes logs inline.
// ---------------------------------------------------------------------------
template<int PRE>
__global__ __launch_bounds__(512) void k_out1(const float* __restrict__ P1,
        const float* __restrict__ P2, const float* __restrict__ Yg,
        const float* __restrict__ X, const float* __restrict__ S,
        f4* __restrict__ out1) {
    const int w = wmap(blockIdx.x);
    f4* __restrict__ dst = out1 + (size_t)w * (BB * 36);

#pragma unroll 4
    for (int j = threadIdx.x; j < BB * 36; j += 512) {
        int b   = j / 36;
        int col = j - b * 36;
        f4 v;
        if (col < 7) {                          // log insample
            int t = w + (col << 2);
            if (PRE) {
                float ll = P1[b * TT + w + 27];
                f4 q = ld4u(P2 + b * TT + t);
                v.x = q.x - ll; v.y = q.y - ll; v.z = q.z - ll; v.w = q.w - ll;
            } else {
                float le = P1[b * TT + w + 27];
                f4 yv = ld4u(Yg + b * TT + t);
                f4 sv = ld4u(P2 + b * SLEN + t);
                v.x = __logf(__fdividef(yv.x, le * sv.x));
                v.y = __logf(__fdividef(yv.y, le * sv.y));
                v.z = __logf(__fdividef(yv.z, le * sv.z));
                v.w = __logf(__fdividef(yv.w, le * sv.w));
            }
        } else if (col < 35) {                  // X windows
            int ch = (col >= 21) ? 1 : 0;
            int t  = w + ((col - 7 - 14 * ch) << 2);
            v = ld4u(X + (size_t)(b * 2 + ch) * TT + t);
        } else {                                // statics
            v = *reinterpret_cast<const f4*>(S + (b << 2));
        }
        __builtin_nontemporal_store(v, dst + j);
    }
}

// ---------------------------------------------------------------------------
// Kernel 4: out2 + out5, w-major. Block owns 2 x 112KB contiguous streams.
// ---------------------------------------------------------------------------
__global__ __launch_bounds__(512) void k_out25(const float* __restrict__ Y,
        const float* __restrict__ M, f4* __restrict__ out2,
        f4* __restrict__ out5) {
    const int w = wmap(blockIdx.x);
    f4* __restrict__ d2 = out2 + (size_t)w * (BB * 7);
    f4* __restrict__ d5 = out5 + (size_t)w * (BB * 7);

#pragma unroll 4
    for (int j = threadIdx.x; j < BB * 7; j += 512) {
        int b   = j / 7;
        int col = j - b * 7;
        int t   = w + NIN + (col << 2);
        f4 vy = ld4u(Y + b * TT + t);
        f4 vm = ld4u(M + b * TT + t);
        __builtin_nontemporal_store(vy, d2 + j);
        __builtin_nontemporal_store(vm, d5 + j);
    }
}

extern "C" void kernel_launch(void* const* d_in, const int* in_sizes, int n_in,
                              void* d_out, int out_size, void* d_ws, size_t ws_size,
                              hipStream_t stream) {
    const float* S    = (const float*)d_in[0];
    const float* Y    = (const float*)d_in[1];
    const float* X    = (const float*)d_in[2];
    const int*   idxs = (const int*)d_in[3];
    const float* mask = (const float*)d_in[4];
    const float* EW   = (const float*)d_in[5];

    float* out  = (float*)d_out;
    float* out1 = out;
    float* out2 = out1 + OUT1_SZ;
    float* out3 = out2 + OUT2_SZ;        // levels
    float* out4 = out3 + OUT3_SZ;        // seasonalities
    float* out5 = out4 + OUT4_SZ;        // mask_w

    es_scan<<<16, 64, 0, stream>>>(Y, idxs, EW, out3, out4);

    const size_t need = (size_t)2 * BB * TT * sizeof(float);   // 4 MB
    if (ws_size >= need) {
        float* LL  = (float*)d_ws;
        float* LYS = LL + BB * TT;
        k_pre<<<512, 256, 0, stream>>>(out3, out4, Y, LL, LYS);
        k_out1<1><<<WW, 512, 0, stream>>>(LL, LYS, Y, X, S, (f4*)out1);
    } else {
        k_out1<0><<<WW, 512, 0, stream>>>(out3, out4, Y, X, S, (f4*)out1);
    }
    k_out25<<<WW, 512, 0, stream>>>(Y, mask, (f4*)out2, (f4*)out5);
}

// Round 14
// 127.753 us; speedup vs baseline: 1.9073x; 1.1698x over previous
//
#include <hip/hip_runtime.h>

#define BB   1024
#define TT   512
#define NIN  28
#define NOUT 28
#define NS   4
#define MM   7
#define WW   457          // TT - NIN - NOUT + 1
#define SLEN 519          // MM + 1 + TT - 1
#define EMB  9            // 1 + 1 + M

#define OUT1_SZ (WW * BB * 144)
#define OUT2_SZ (WW * BB * 28)
#define OUT3_SZ (BB * TT)
#define OUT4_SZ (BB * SLEN)

#define CH   32
#define NCH  (TT / CH)    // 16
#define NF2  (WW * BB * 7)

typedef float f4 __attribute__((ext_vector_type(4)));

__device__ __forceinline__ f4 ld4u(const float* p) {   // 4B-aligned 16B load
    f4 v;
    __builtin_memcpy(&v, p, sizeof(f4));
    return v;
}

// ---------------------------------------------------------------------------
// Kernel 1: ES scan (R4 version, proven ~10 us).
// ---------------------------------------------------------------------------
__global__ __launch_bounds__(64) void es_scan(const float* __restrict__ Y,
        const int* __restrict__ idxs, const float* __restrict__ EW,
        float* __restrict__ levels, float* __restrict__ seas) {
    __shared__ float yl[64][CH + 1];
    __shared__ float se[64][CH + 1];
    const int tid = threadIdx.x;
    const int b0  = blockIdx.x << 6;
    const int b   = b0 + tid;

    const float* e = EW + idxs[b] * EMB;
    const float lev_sms  = 1.0f / (1.0f + __expf(-e[0]));
    const float seas_sms = 1.0f / (1.0f + __expf(-e[1]));
    const float a_l = 1.0f - lev_sms;
    const float a_s = 1.0f - seas_sms;

    float buf[MM];
    const float is0 = __expf(e[2]);
    {
        float* srow = seas + b * SLEN;
        srow[0] = is0;
#pragma unroll
        for (int k = 1; k < MM; ++k) {
            float v = __expf(e[2 + k]);
            srow[k] = v;
            buf[k - 1] = v;
        }
        buf[MM - 1] = is0;
    }

    f4 pf[8];
#pragma unroll
    for (int k = 0; k < 8; ++k) {
        int flat = (k << 6) + tid;
        int r = flat >> 3, q = flat & 7;
        pf[k] = *reinterpret_cast<const f4*>(Y + (b0 + r) * TT + (q << 2));
    }

    float lev = 0.0f;

#define ES_STEP(TTI)                                                        \
    {                                                                       \
        float y  = yreg[TTI];                                               \
        float st = buf[0];                                                  \
        lev = lev_sms * __fdividef(y, st) + a_l * lev;                      \
        float ns = seas_sms * __fdividef(y, lev) + a_s * st;                \
        buf[0] = buf[1]; buf[1] = buf[2]; buf[2] = buf[3];                  \
        buf[3] = buf[4]; buf[4] = buf[5]; buf[5] = buf[6];                  \
        buf[6] = ns;                                                        \
        yl[tid][TTI] = lev;                                                 \
        se[tid][TTI] = ns;                                                  \
    }

    for (int c = 0; c < NCH; ++c) {
        __syncthreads();
#pragma unroll
        for (int k = 0; k < 8; ++k) {
            int flat = (k << 6) + tid;
            int r = flat >> 3, q = flat & 7;
            float* dst = &yl[r][q << 2];
            dst[0] = pf[k].x; dst[1] = pf[k].y; dst[2] = pf[k].z; dst[3] = pf[k].w;
        }
        __syncthreads();
        if (c < NCH - 1) {
#pragma unroll
            for (int k = 0; k < 8; ++k) {
                int flat = (k << 6) + tid;
                int r = flat >> 3, q = flat & 7;
                pf[k] = *reinterpret_cast<const f4*>(
                    Y + (b0 + r) * TT + (c + 1) * CH + (q << 2));
            }
        }

        float yreg[CH];
#pragma unroll
        for (int tt = 0; tt < CH; ++tt) yreg[tt] = yl[tid][tt];

        if (c == 0) {
            lev = __fdividef(yreg[0], is0);
            yl[tid][0] = lev;
            se[tid][0] = is0;
#pragma unroll
            for (int tt = 1; tt < CH; ++tt) ES_STEP(tt)
        } else {
#pragma unroll
            for (int tt = 0; tt < CH; ++tt) ES_STEP(tt)
        }
        __syncthreads();

#pragma unroll
        for (int k = 0; k < CH; ++k) {
            int flat = (k << 6) + tid;
            int r    = flat >> 5;
            int col  = flat & 31;
            levels[(b0 + r) * TT   + c * CH + col]      = yl[r][col];
            seas  [(b0 + r) * SLEN + MM + c * CH + col] = se[r][col];
        }
    }
#undef ES_STEP
}

// ---------------------------------------------------------------------------
// Kernel 2: out1 — branchless constant-stride inner loop.
// Block = (b-pair) x (w-half). LDS: 4 shifted replicas of LYS=[logY-logSeas]
// (64 f4 slots per s,bl) and X (72 slots per s,bl,ch) + S slots + zero;
// LLf = log(levels) + zero float. 31 KB -> 4 blocks/CU, 100% occupancy.
// Every lane: identical sequence {ds_read_b128, ds_read_b32(broadcast),
// 4 subs, nt store, 3 pointer bumps}; per-lane precomputed address deltas
// encode the replica rotation. Stores are full-wave dense (off = base+lane).
// ---------------------------------------------------------------------------
#define SBLK 420          // f4 slots per s-replica block
#define D0q  (3 * SBLK + 1)   // delta when current s == 0
#define D1q  (2 - SBLK)       // delta otherwise
#define OST  (7 * 1024 * 36)  // store advance per step (f4)

__global__ __launch_bounds__(512) void k_out1(const float* __restrict__ Y,
        const float* __restrict__ X, const float* __restrict__ S,
        const float* __restrict__ levels, const float* __restrict__ seas,
        f4* __restrict__ out1) {
    __shared__ f4    R[4 * SBLK + 3];     // 1683 f4 = 26,928 B
    __shared__ float LLf[1026];           // [bl*512+t], [1024]=0

    const int tid = threadIdx.x;
    const int p   = blockIdx.x >> 1;      // b-pair 0..511
    const int h   = blockIdx.x & 1;       // w-half
    const int b0  = p << 1;
    const int g0  = h ? 229 : 0;
    const int NW  = h ? 228 : 229;

    // ---- stage LYS replicas: 512 slots, one per thread ----
    {
        int s = tid >> 7, bl = (tid >> 6) & 1, k = tid & 63;
        int base = g0 + 4 * k + s;                   // <= 487
        f4 yv = ld4u(Y    + (b0 + bl) * TT   + base);
        f4 sv = ld4u(seas + (b0 + bl) * SLEN + base);
        f4 v;
        v.x = __logf(yv.x) - __logf(sv.x);
        v.y = __logf(yv.y) - __logf(sv.y);
        v.z = __logf(yv.z) - __logf(sv.z);
        v.w = __logf(yv.w) - __logf(sv.w);
        R[s * SBLK + bl * 64 + k] = v;
    }
    // ---- stage X replicas: 1152 slots ----
    for (int u = tid; u < 1152; u += 512) {
        int s = u / 288, rem = u - s * 288;
        int blc = rem / 72, k = rem - blc * 72;      // blc = bl*2+ch
        int base = g0 + 4 * k + s;
        if (base > 508) base = 508;                  // clamp (slot unused)
        R[s * SBLK + 128 + blc * 72 + k] =
            ld4u(X + (size_t)((b0 + (blc >> 1)) * 2 + (blc & 1)) * TT + base);
    }
    // ---- LL = log(levels) ----
    for (int u = tid; u < 1024; u += 512)
        LLf[u] = __logf(levels[(b0 + (u >> 9)) * TT + (u & 511)]);
    if (tid < 2) R[4 * SBLK + tid] = *reinterpret_cast<const f4*>(S + (b0 + tid) * NS);
    if (tid == 2) { f4 z; z.x = z.y = z.z = z.w = 0.0f; R[4 * SBLK + 2] = z; }
    if (tid == 3) LLf[1024] = 0.0f;
    __syncthreads();

    if (tid < 504) {
        const int go  = tid / 72;                    // 0..6 (g-lane)
        const int r   = tid - go * 72;
        const int bl  = (r >= 36) ? 1 : 0;
        const int col = r - 36 * bl;                 // 0..35
        const int s0  = go & 3;
        const int wh0 = go >> 2;

        int qa, la, ls, mv;
        if (col < 7) {                               // log insample
            qa = s0 * SBLK + bl * 64 + wh0 + col;
            la = bl * 512 + g0 + go + 27;
            ls = 7;  mv = 1;
        } else if (col < 35) {                       // X windows
            int ch = (col >= 21) ? 1 : 0;
            int jj = col - 7 - 14 * ch;
            qa = s0 * SBLK + 128 + (bl * 2 + ch) * 72 + wh0 + jj;
            la = 1024;  ls = 0;  mv = 1;
        } else {                                     // statics
            qa = 4 * SBLK + bl;
            la = 1024;  ls = 0;  mv = 0;
        }
        // per-unroll-slot deltas: s at slot j is (s0+3j)&3
        const int dA = mv ? ((((s0    ) & 3) == 0) ? D0q : D1q) : 0;
        const int dB = mv ? ((((s0 + 3) & 3) == 0) ? D0q : D1q) : 0;
        const int dC = mv ? ((((s0 + 2) & 3) == 0) ? D0q : D1q) : 0;
        const int dD = mv ? ((((s0 + 1) & 3) == 0) ? D0q : D1q) : 0;
        int off = (((g0 + go) << 10) + b0 + bl) * 36 + col;

#define STEP1(DQ)                                                           \
        { f4 q = R[qa]; float l = LLf[la];                                  \
          f4 v; v.x = q.x - l; v.y = q.y - l; v.z = q.z - l; v.w = q.w - l; \
          __builtin_nontemporal_store(v, out1 + off);                       \
          qa += DQ; la += ls; off += OST; }

        for (int it = 0; it < 8; ++it) {             // 32 unconditional steps
            STEP1(dA) STEP1(dB) STEP1(dC) STEP1(dD)
        }
        if (go + 224 < NW) STEP1(dA)                 // tail (step 33)
#undef STEP1
    }
}

// ---------------------------------------------------------------------------
// Kernel 3: out2 + out5 (R10 version, flat dense, nt stores).
// ---------------------------------------------------------------------------
__global__ __launch_bounds__(256) void k_out25(const float* __restrict__ Y,
        const float* __restrict__ mask, f4* __restrict__ out2,
        f4* __restrict__ out5) {
    int i = blockIdx.x * blockDim.x + threadIdx.x;
    const int stride = gridDim.x * blockDim.x;
    for (; i < NF2; i += stride) {
        int wb = i / 7;
        int j  = i - wb * 7;
        int b  = wb & (BB - 1);
        int w  = wb >> 10;
        int base = w + NIN + (j << 2);
        f4 vy = ld4u(Y    + b * TT + base);
        f4 vm = ld4u(mask + b * TT + base);
        __builtin_nontemporal_store(vy, &out2[i]);
        __builtin_nontemporal_store(vm, &out5[i]);
    }
}

extern "C" void kernel_launch(void* const* d_in, const int* in_sizes, int n_in,
                              void* d_out, int out_size, void* d_ws, size_t ws_size,
                              hipStream_t stream) {
    const float* S    = (const float*)d_in[0];
    const float* Y    = (const float*)d_in[1];
    const float* X    = (const float*)d_in[2];
    const int*   idxs = (const int*)d_in[3];
    const float* mask = (const float*)d_in[4];
    const float* EW   = (const float*)d_in[5];

    float* out  = (float*)d_out;
    float* out1 = out;
    float* out2 = out1 + OUT1_SZ;
    float* out3 = out2 + OUT2_SZ;        // levels
    float* out4 = out3 + OUT3_SZ;        // seasonalities
    float* out5 = out4 + OUT4_SZ;        // mask_w

    es_scan<<<16, 64, 0, stream>>>(Y, idxs, EW, out3, out4);
    k_out1<<<1024, 512, 0, stream>>>(Y, X, S, out3, out4, (f4*)out1);
    k_out25<<<2048, 256, 0, stream>>>(Y, mask, (f4*)out2, (f4*)out5);
}